// Round 5
// baseline (239.134 us; speedup 1.0000x reference)
//
#include <hip/hip_runtime.h>

#define BB 512
#define SS 512
#define TT 78
#define TP 80      // padded tag count (multiple of 4)
#define NT 128     // 2 waves: wave0 = score chain, wave1 = alpha chain

typedef float v2f __attribute__((ext_vector_type(2)));
typedef float v4f __attribute__((ext_vector_type(4)));

__device__ __forceinline__ float fexp(float x) { return __expf(x); }
__device__ __forceinline__ float flog(float x) { return __logf(x); }

// Source-level static loop: body sees the index as a TEMPLATE CONSTANT, so
// array subscripts are constant-index GEPs at the AST level -> the FIRST SROA
// pass promotes the arrays. (#pragma unroll unrolls AFTER SROA -> scratch;
// this was the VGPR_Count=132 bug of rounds 2-4.)
template<int I> struct ic { static constexpr int v = I; };
template<int I, int N, typename F>
__device__ __forceinline__ void sfor(F f) {
    if constexpr (I < N) {
        f(ic<I>{});
        sfor<I + 1, N>(f);
    }
}

__global__ __launch_bounds__(NT, 1) void crf_fwd_kernel(
    const float* __restrict__ em,          // [B,S,T]
    const unsigned int* __restrict__ mi32, // [B,S] int32 OR packed bool bytes
    const float* __restrict__ st,          // [T]
    const float* __restrict__ en_,         // [T]
    const float* __restrict__ tr,          // [T,T] row j (src), col t (dst)
    float* __restrict__ out)               // [B]
{
    const int b    = blockIdx.x;
    const int tid  = threadIdx.x;
    const int wid  = tid >> 6;            // 0 = score (masked), 1 = alpha
    const int lane = tid & 63;
    const bool has2 = lane < (TT - 64);   // lanes 0..13 own a second tag
    const int t0  = lane;                 // always < 78
    const int t1  = lane + 64;
    const int t1c = has2 ? t1 : (TT - 1); // clamped index for safe loads

    __shared__ __align__(16) float sE[2][TP];  // per-wave exp-state vector
    __shared__ float sfin[2];
    __shared__ int sflag;

    // ---- one-time mask layout detection (int32 elements vs 1-byte bools) ----
    if (tid == 0) sflag = 1;
    __syncthreads();
    {
        bool okl = true;
        for (int k = tid; k < 512; k += NT) okl = okl && (mi32[k] <= 1u);
        if (!okl) atomicAnd(&sflag, 0);
    }
    __syncthreads();
    const bool mask_int = (sflag != 0);
    const unsigned char* mi8 = (const unsigned char*)mi32;
    const bool is_alpha = (wid == 1);

    // ---- preload exp(trans[j][t]) columns for my two tags into REGISTERS ----
    v2f et0[TP / 2];   // et0[p] = {exp(tr[2p][t0]),  exp(tr[2p+1][t0])}
    v2f et1[TP / 2];   // et1[p] = {exp(tr[2p][t1c]), exp(tr[2p+1][t1c])}
    sfor<0, TP / 2>([&](auto P) {
        constexpr int p  = decltype(P)::v;
        constexpr int j0 = 2 * p, j1 = 2 * p + 1;
        float a0v = (j0 < TT) ? fexp(tr[j0 * TT + t0])  : 0.0f;
        float a1v = (j1 < TT) ? fexp(tr[j1 * TT + t0])  : 0.0f;
        float b0v = (j0 < TT) ? fexp(tr[j0 * TT + t1c]) : 0.0f;
        float b1v = (j1 < TT) ? fexp(tr[j1 * TT + t1c]) : 0.0f;
        et0[p] = (v2f){a0v, a1v};
        et1[p] = (v2f){b0v, b1v};
    });

    // ---- init state: start + emissions[:,0] ----
    const size_t base = (size_t)b * SS * TT;
    float sc0 = st[t0] + em[base + t0];
    float sc1 = st[t1c] + em[base + t1c];   // junk for !has2, never used

    // zero the LDS padding entries (written once, never overwritten)
    if (lane == 14 || lane == 15) sE[wid][64 + lane] = 0.f;  // slots 78, 79

    // ---- prefetch step 1 ----
    const float* rp = em + base + TT;
    float en0 = rp[t0];
    float en1 = rp[t1c];
    unsigned int mk_n = mask_int ? mi32[b * SS + 1] : (unsigned int)mi8[b * SS + 1];

    for (int i = 1; i < SS; ++i) {
        // broadcast m = state[0] (lane 0's t0 value) via SALU
        float m = __builtin_amdgcn_readfirstlane(sc0);
        sE[wid][lane] = fexp(sc0 - m);
        if (has2) sE[wid][64 + lane] = fexp(sc1 - m);

        const float emi0 = en0, emi1 = en1;
        const unsigned int mki = mk_n;
        if (i + 1 < SS) {                   // prefetch next step
            rp += TT;
            en0 = rp[t0];
            en1 = rp[t1c];
            mk_n = mask_int ? mi32[b * SS + i + 1] : (unsigned int)mi8[b * SS + i + 1];
        }
        __builtin_amdgcn_wave_barrier();    // keep reads after writes (no HW cost)

        // ---- load the ENTIRE exp-state vector into registers first ----
        const v4f* ep = (const v4f*)sE[wid];
        v4f xs[TP / 4];
        sfor<0, TP / 4>([&](auto K) {
            constexpr int k = decltype(K)::v;
            xs[k] = ep[k];
        });

        // matvec: v[t] = sum_j E[j] * exp(trans[j][t]); packed fp32 FMAs
        v2f a0 = {0.f, 0.f}, a1 = {0.f, 0.f};   // accumulators for t0
        v2f c0 = {0.f, 0.f}, c1 = {0.f, 0.f};   // accumulators for t1
        sfor<0, TP / 4>([&](auto K) {           // 20 steps, 4 pk-FMA each
            constexpr int k = decltype(K)::v;
            v2f xlo = {xs[k].x, xs[k].y};
            v2f xhi = {xs[k].z, xs[k].w};
            a0 = __builtin_elementwise_fma(xlo, et0[2 * k + 0], a0);
            a1 = __builtin_elementwise_fma(xhi, et0[2 * k + 1], a1);
            c0 = __builtin_elementwise_fma(xlo, et1[2 * k + 0], c0);
            c1 = __builtin_elementwise_fma(xhi, et1[2 * k + 1], c1);
        });
        v2f va = a0 + a1;
        v2f vc = c0 + c1;
        float v0 = va.x + va.y;
        float v1 = vc.x + vc.y;

        float nsc0 = emi0 + m + flog(v0);
        float nsc1 = emi1 + m + flog(v1);
        const bool upd = is_alpha | (mki != 0);   // alpha always updates
        sc0 = upd ? nsc0 : sc0;
        sc1 = upd ? nsc1 : sc1;
    }

    // ---- final: lse over tags with end transitions (in-wave reduce) ----
    float f0 = sc0 + en_[t0];
    float f1 = has2 ? (sc1 + en_[t1c]) : -1e30f;
    float mm = fmaxf(f0, f1);
    #pragma unroll
    for (int o = 32; o > 0; o >>= 1) mm = fmaxf(mm, __shfl_xor(mm, o));
    float s = fexp(f0 - mm) + (has2 ? fexp(f1 - mm) : 0.f);
    #pragma unroll
    for (int o = 32; o > 0; o >>= 1) s += __shfl_xor(s, o);
    if (lane == 0) sfin[wid] = mm + flog(s);
    __syncthreads();
    if (tid == 0) out[b] = sfin[1] - sfin[0];   // partition - score_final
}

extern "C" void kernel_launch(void* const* d_in, const int* in_sizes, int n_in,
                              void* d_out, int out_size, void* d_ws, size_t ws_size,
                              hipStream_t stream) {
    const float* emissions    = (const float*)d_in[0];
    const unsigned int* mask  = (const unsigned int*)d_in[1];
    const float* start_trans  = (const float*)d_in[2];
    const float* end_trans    = (const float*)d_in[3];
    const float* transitions  = (const float*)d_in[4];
    float* out = (float*)d_out;

    crf_fwd_kernel<<<BB, NT, 0, stream>>>(emissions, mask, start_trans,
                                          end_trans, transitions, out);
}

// Round 6
// 238.488 us; speedup vs baseline: 1.0027x; 1.0027x over previous
//
#include <hip/hip_runtime.h>

#define BB 512
#define SS 512
#define TT 78
#define TP 80      // padded tag count (multiple of 4)
#define NT 128     // 2 waves: wave0 = score chain, wave1 = alpha chain

typedef float v2f __attribute__((ext_vector_type(2)));
typedef float v4f __attribute__((ext_vector_type(4)));

__device__ __forceinline__ float fexp(float x) { return __expf(x); }
__device__ __forceinline__ float flog(float x) { return __logf(x); }

// Source-level static loop: body sees the index as a TEMPLATE CONSTANT.
template<int I> struct ic { static constexpr int v = I; };
template<int I, int N, typename F>
__device__ __forceinline__ void sfor(F f) {
    if constexpr (I < N) {
        f(ic<I>{});
        sfor<I + 1, N>(f);
    }
}

// amdgpu_waves_per_eu(1,1): command the register allocator's occupancy target
// directly. Grid supplies exactly 1 wave/SIMD (1024 waves on 1024 SIMDs), so
// forcing occupancy 1 costs nothing and unlocks the full 512-VGPR budget —
// rounds 2-5 showed the allocator refusing >132 VGPRs (et/xs demoted to
// scratch / 2-deep serialized LDS reads) under __launch_bounds__(128,1).
__global__ __attribute__((amdgpu_flat_work_group_size(NT, NT),
                          amdgpu_waves_per_eu(1, 1)))
void crf_fwd_kernel(
    const float* __restrict__ em,          // [B,S,T]
    const unsigned int* __restrict__ mi32, // [B,S] int32 OR packed bool bytes
    const float* __restrict__ st,          // [T]
    const float* __restrict__ en_,         // [T]
    const float* __restrict__ tr,          // [T,T] row j (src), col t (dst)
    float* __restrict__ out)               // [B]
{
    const int b    = blockIdx.x;
    const int tid  = threadIdx.x;
    const int wid  = tid >> 6;            // 0 = score (masked), 1 = alpha
    const int lane = tid & 63;
    const bool has2 = lane < (TT - 64);   // lanes 0..13 own a second tag
    const int t0  = lane;                 // always < 78
    const int t1  = lane + 64;
    const int t1c = has2 ? t1 : (TT - 1); // clamped index for safe loads

    __shared__ __align__(16) float sE[2][TP];  // per-wave exp-state vector
    __shared__ float sfin[2];
    __shared__ int sflag;

    // ---- one-time mask layout detection (int32 elements vs 1-byte bools) ----
    if (tid == 0) sflag = 1;
    __syncthreads();
    {
        bool okl = true;
        for (int k = tid; k < 512; k += NT) okl = okl && (mi32[k] <= 1u);
        if (!okl) atomicAnd(&sflag, 0);
    }
    __syncthreads();
    const bool mask_int = (sflag != 0);
    const unsigned char* mi8 = (const unsigned char*)mi32;
    const bool is_alpha = (wid == 1);

    // ---- preload exp(trans[j][t]) columns for my two tags into REGISTERS ----
    v2f et0[TP / 2];   // et0[p] = {exp(tr[2p][t0]),  exp(tr[2p+1][t0])}
    v2f et1[TP / 2];   // et1[p] = {exp(tr[2p][t1c]), exp(tr[2p+1][t1c])}
    sfor<0, TP / 2>([&](auto P) {
        constexpr int p  = decltype(P)::v;
        constexpr int j0 = 2 * p, j1 = 2 * p + 1;
        float a0v = (j0 < TT) ? fexp(tr[j0 * TT + t0])  : 0.0f;
        float a1v = (j1 < TT) ? fexp(tr[j1 * TT + t0])  : 0.0f;
        float b0v = (j0 < TT) ? fexp(tr[j0 * TT + t1c]) : 0.0f;
        float b1v = (j1 < TT) ? fexp(tr[j1 * TT + t1c]) : 0.0f;
        et0[p] = (v2f){a0v, a1v};
        et1[p] = (v2f){b0v, b1v};
    });

    // ---- init state: start + emissions[:,0] ----
    const size_t base = (size_t)b * SS * TT;
    float sc0 = st[t0] + em[base + t0];
    float sc1 = st[t1c] + em[base + t1c];   // junk for !has2, never used

    // zero the LDS padding entries (written once, never overwritten)
    if (lane == 14 || lane == 15) sE[wid][64 + lane] = 0.f;  // slots 78, 79

    // ---- prefetch step 1 ----
    const float* rp = em + base + TT;
    float en0 = rp[t0];
    float en1 = rp[t1c];
    unsigned int mk_n = mask_int ? mi32[b * SS + 1] : (unsigned int)mi8[b * SS + 1];

    for (int i = 1; i < SS; ++i) {
        // broadcast m = state[0] (lane 0's t0 value) via SALU
        float m = __builtin_amdgcn_readfirstlane(sc0);
        sE[wid][lane] = fexp(sc0 - m);
        if (has2) sE[wid][64 + lane] = fexp(sc1 - m);

        const float emi0 = en0, emi1 = en1;
        const unsigned int mki = mk_n;
        if (i + 1 < SS) {                   // prefetch next step
            rp += TT;
            en0 = rp[t0];
            en1 = rp[t1c];
            mk_n = mask_int ? mi32[b * SS + i + 1] : (unsigned int)mi8[b * SS + i + 1];
        }
        __builtin_amdgcn_wave_barrier();    // keep reads after writes (no HW cost)

        // ---- load the ENTIRE exp-state vector into registers first ----
        const v4f* ep = (const v4f*)sE[wid];
        v4f xs[TP / 4];
        sfor<0, TP / 4>([&](auto K) {
            constexpr int k = decltype(K)::v;
            xs[k] = ep[k];
        });

        // matvec: v[t] = sum_j E[j] * exp(trans[j][t]); packed fp32 FMAs
        v2f a0 = {0.f, 0.f}, a1 = {0.f, 0.f};   // accumulators for t0
        v2f c0 = {0.f, 0.f}, c1 = {0.f, 0.f};   // accumulators for t1
        sfor<0, TP / 4>([&](auto K) {           // 20 steps, 4 pk-FMA each
            constexpr int k = decltype(K)::v;
            v2f xlo = {xs[k].x, xs[k].y};
            v2f xhi = {xs[k].z, xs[k].w};
            a0 = __builtin_elementwise_fma(xlo, et0[2 * k + 0], a0);
            a1 = __builtin_elementwise_fma(xhi, et0[2 * k + 1], a1);
            c0 = __builtin_elementwise_fma(xlo, et1[2 * k + 0], c0);
            c1 = __builtin_elementwise_fma(xhi, et1[2 * k + 1], c1);
        });
        v2f va = a0 + a1;
        v2f vc = c0 + c1;
        float v0 = va.x + va.y;
        float v1 = vc.x + vc.y;

        float nsc0 = emi0 + m + flog(v0);
        float nsc1 = emi1 + m + flog(v1);
        const bool upd = is_alpha | (mki != 0);   // alpha always updates
        sc0 = upd ? nsc0 : sc0;
        sc1 = upd ? nsc1 : sc1;
    }

    // ---- final: lse over tags with end transitions (in-wave reduce) ----
    float f0 = sc0 + en_[t0];
    float f1 = has2 ? (sc1 + en_[t1c]) : -1e30f;
    float mm = fmaxf(f0, f1);
    #pragma unroll
    for (int o = 32; o > 0; o >>= 1) mm = fmaxf(mm, __shfl_xor(mm, o));
    float s = fexp(f0 - mm) + (has2 ? fexp(f1 - mm) : 0.f);
    #pragma unroll
    for (int o = 32; o > 0; o >>= 1) s += __shfl_xor(s, o);
    if (lane == 0) sfin[wid] = mm + flog(s);
    __syncthreads();
    if (tid == 0) out[b] = sfin[1] - sfin[0];   // partition - score_final
}

extern "C" void kernel_launch(void* const* d_in, const int* in_sizes, int n_in,
                              void* d_out, int out_size, void* d_ws, size_t ws_size,
                              hipStream_t stream) {
    const float* emissions    = (const float*)d_in[0];
    const unsigned int* mask  = (const unsigned int*)d_in[1];
    const float* start_trans  = (const float*)d_in[2];
    const float* end_trans    = (const float*)d_in[3];
    const float* transitions  = (const float*)d_in[4];
    float* out = (float*)d_out;

    crf_fwd_kernel<<<BB, NT, 0, stream>>>(emissions, mask, start_trans,
                                          end_trans, transitions, out);
}